// Round 1
// 304.273 us; speedup vs baseline: 1.0390x; 1.0390x over previous
//
#include <hip/hip_runtime.h>

typedef unsigned short u16;
using u16x4  = __attribute__((ext_vector_type(4))) unsigned short;
using u16x8  = __attribute__((ext_vector_type(8))) unsigned short;
using bf16x8 = __attribute__((ext_vector_type(8))) short;
using f32x4  = __attribute__((ext_vector_type(4))) float;
using f32x16 = __attribute__((ext_vector_type(16))) float;

// ---------- helpers ----------
__device__ __forceinline__ u16 f2bf(float f) {
  union { float f; unsigned u; } v; v.f = f;
  unsigned r = v.u + 0x7FFFu + ((v.u >> 16) & 1u);  // RNE (inputs bounded, no NaN)
  return (u16)(r >> 16);
}

__device__ __forceinline__ unsigned cvt_pk_bf16(float a, float b) {
  unsigned d;
  asm("v_cvt_pk_bf16_f32 %0, %1, %2" : "=v"(d) : "v"(a), "v"(b));
  return d;  // low16 = bf16(a), high16 = bf16(b)
}

// ---------- pre-pass 1: x fp32 -> bf16 ----------
__global__ void convert_x_k(const float* __restrict__ in, u16* __restrict__ out) {
  int i = blockIdx.x * 256 + threadIdx.x;
  float4 v = ((const float4*)in)[i];
  u16x4 u;
  u.x = f2bf(v.x); u.y = f2bf(v.y); u.z = f2bf(v.z); u.w = f2bf(v.w);
  ((u16x4*)out)[i] = u;
}

// ---------- pre-pass 2: W [mat][i][h] fp32 -> blocked bf16 [mat][i/16][h][16] ----------
// element (i,h) -> (i>>4)*4096 + h*16 + (i&15)   (A-operand layout for mfma_32x32x16,
// lane m = l&31 reads 8 consecutive k at k = ch*16 + (l>>5)*8)
__global__ __launch_bounds__(256) void transpose_w2_k(
    const float* __restrict__ W1, const float* __restrict__ W2,
    u16* __restrict__ w1t, u16* __restrict__ w2t) {
  __shared__ float tile[64][65];
  const int bid = blockIdx.x;
  const int mat = bid >> 4;
  const int tl  = bid & 15;
  const int i0 = (tl >> 2) * 64, h0 = (tl & 3) * 64;
  const float* src = (mat < 256) ? (W1 + mat * 65536) : (W2 + (mat - 256) * 65536);
  u16*       dst   = (mat < 256) ? (w1t + mat * 65536) : (w2t + (mat - 256) * 65536);
  const int t = threadIdx.x;
#pragma unroll
  for (int j = 0; j < 4; ++j) {
    int lin = j * 256 + t;
    int row = lin >> 4, c4 = lin & 15;
    float4 v = *(const float4*)(src + (i0 + row) * 256 + h0 + c4 * 4);
    tile[row][c4 * 4 + 0] = v.x; tile[row][c4 * 4 + 1] = v.y;
    tile[row][c4 * 4 + 2] = v.z; tile[row][c4 * 4 + 3] = v.w;
  }
  __syncthreads();
  const int col = t >> 2;            // h = h0 + col
  const int kk  = (t & 3) * 8;       // 0,8,16,24
#pragma unroll
  for (int p = 0; p < 2; ++p) {      // two 32-row sub-stripes per 64-row tile
    u16x8 o;
#pragma unroll
    for (int jj = 0; jj < 8; ++jj)
      o[jj] = f2bf(tile[p * 32 + kk + jj][col]);
    // i = i0 + p*32 + kk + jj  ->  chunk = i>>4, low = i&15
    *(u16x8*)(dst + ((i0 >> 4) + 2 * p + (kk >> 4)) * 4096 + (h0 + col) * 16 + (kk & 8)) = o;
  }
}

// ---------- main fused kernel (transposed formulation, 32x32x16 MFMA) ----------
// Block = (subcarrier c, 128-row batch tile). 512 threads = 8 waves.
// Wave (wq = w&3, bh = w>>2): out-cols m_base=wq*64 (2 frags of 32), batch rows
// n_base=bh*64 (2 frags of 32). A = W^T from global (blocked layout, b128, L2-resident),
// B = x/H1 rows from LDS row-major (contiguous b128, 2-way bank alias = free).
// C/D: col(lane&31)=batch row, row(reg)=out-col -> epilogues are in-lane:
//  - bias folded into acc init (wave-uniform s_load + one hi/lo cndmask)
//  - H1 store: cvt_pk_bf16 pairs -> b64 (4 consecutive out-cols per lane-group)
//  - final dot with W3 fully in-lane, zero shuffles.
__global__ __launch_bounds__(512, 4) void rf_main_k(
    const u16* __restrict__ xb, const u16* __restrict__ w1t, const u16* __restrict__ w2t,
    const float* __restrict__ b1, const float* __restrict__ b2,
    const float* __restrict__ w3, const float* __restrict__ b3,
    float* __restrict__ out) {
  __shared__ u16 sH[128 * 264];        // x-tile, then H1 (in place), stride 264
  __shared__ float red[8 * 128];       // (wq*2+hi) x 128 rows

  const int bid  = blockIdx.x;
  const int xcd  = bid & 7;
  const int j8   = bid >> 3;
  const int c    = xcd * 32 + (j8 >> 4);
  const int b0   = (j8 & 15) * 128;
  const int t    = threadIdx.x;
  const int lane = t & 63;
  const int w    = t >> 6;
  const int l31  = lane & 31;
  const int hi   = lane >> 5;
  const bool hiH = hi != 0;
  const int wq   = w & 3;
  const int bh   = w >> 2;
  const int m_base = wq * 64;
  const int n_base = bh * 64;

  const u16* w1c = w1t + c * 65536;
  const u16* w2c = w2t + c * 65536;
  // A (weights, global): + ch*4096 + mi*512
  const int aoff = (m_base + l31) * 16 + hi * 8;
  // B (x/H1, LDS): + ch*16 + nj*8448
  const int bbase = (n_base + l31) * 264 + hi * 8;
  // wave-uniform column base for bias/w3 scalar loads
  const int bidx = __builtin_amdgcn_readfirstlane(c * 256 + m_base);

  f32x16 acc[2][2];
  bf16x8 aA[2], aB[2];

#define LOADA(dst, base)                                         \
  { dst[0] = *(const bf16x8*)(base);                             \
    dst[1] = *(const bf16x8*)((base) + 512); }

#define COMPUTE(fr, ch)                                          \
  { bf16x8 _b0 = *(const bf16x8*)&sH[bbase + (ch) * 16];         \
    bf16x8 _b1 = *(const bf16x8*)&sH[bbase + (ch) * 16 + 8448];  \
    acc[0][0] = __builtin_amdgcn_mfma_f32_32x32x16_bf16(fr[0], _b0, acc[0][0], 0, 0, 0); \
    acc[1][0] = __builtin_amdgcn_mfma_f32_32x32x16_bf16(fr[1], _b0, acc[1][0], 0, 0, 0); \
    acc[0][1] = __builtin_amdgcn_mfma_f32_32x32x16_bf16(fr[0], _b1, acc[0][1], 0, 0, 0); \
    acc[1][1] = __builtin_amdgcn_mfma_f32_32x32x16_bf16(fr[1], _b1, acc[1][1], 0, 0, 0); }

  // acc init = bias (wave-uniform per reg up to the hi/lo half-wave select)
#define INIT_ACC(bp)                                             \
  { _Pragma("unroll")                                            \
    for (int _mi = 0; _mi < 2; ++_mi) {                          \
      _Pragma("unroll")                                          \
      for (int _g = 0; _g < 4; ++_g) {                           \
        f32x4 _lo = *(const f32x4*)((bp) + bidx + _mi * 32 + _g * 8);     \
        f32x4 _h4 = *(const f32x4*)((bp) + bidx + _mi * 32 + _g * 8 + 4); \
        _Pragma("unroll")                                        \
        for (int _r = 0; _r < 4; ++_r) {                         \
          float _v = hiH ? _h4[_r] : _lo[_r];                    \
          acc[_mi][0][_g * 4 + _r] = _v;                         \
          acc[_mi][1][_g * 4 + _r] = _v;                         \
        } } } }

  // prefetch W1 chunk 0 while staging x
  LOADA(aA, w1c + aoff);

  // stage x-tile: 128 rows x 256 u16 -> sH stride 264
#pragma unroll
  for (int i = 0; i < 8; ++i) {
    int flat = i * 512 + t;
    int r = flat >> 5, s = flat & 31;
    u16x8 g = *(const u16x8*)(xb + (b0 + r) * 256 + s * 8);
    *(u16x8*)&sH[r * 264 + s * 8] = g;
  }
  INIT_ACC(b1);
  __syncthreads();

  // ========== Phase A: H1^T = W1^T . x^T (+b1, relu), barrier-free K-loop ==========
#pragma unroll 1
  for (int ch = 0; ch < 16; ch += 2) {
    LOADA(aB, w1c + (ch + 1) * 4096 + aoff);
    COMPUTE(aA, ch);
    const u16* nxt = (ch == 14) ? (w2c + aoff)
                                : (w1c + (ch + 2) * 4096 + aoff);
    LOADA(aA, nxt);
    COMPUTE(aB, ch + 1);
  }

  // Phase A epilogue: relu -> bf16 H1, in place over sX (b64 stores, in-lane packing)
  __syncthreads();                     // all x reads retired
#pragma unroll
  for (int mi = 0; mi < 2; ++mi)
#pragma unroll
    for (int nj = 0; nj < 2; ++nj) {
      const int row = n_base + nj * 32 + l31;
#pragma unroll
      for (int g = 0; g < 4; ++g) {
        float v0 = fmaxf(acc[mi][nj][g * 4 + 0], 0.f);
        float v1 = fmaxf(acc[mi][nj][g * 4 + 1], 0.f);
        float v2 = fmaxf(acc[mi][nj][g * 4 + 2], 0.f);
        float v3 = fmaxf(acc[mi][nj][g * 4 + 3], 0.f);
        uint2 p;
        p.x = cvt_pk_bf16(v0, v1);
        p.y = cvt_pk_bf16(v2, v3);
        *(uint2*)&sH[row * 264 + m_base + mi * 32 + g * 8 + 4 * hi] = p;
      }
    }
  INIT_ACC(b2);
  __syncthreads();                     // H1 published

  // ========== Phase B: H2^T = W2^T . H1^T (+b2, relu), then in-lane dot W3 ==========
#pragma unroll 1
  for (int ch = 0; ch < 16; ch += 2) {
    LOADA(aB, w2c + (ch + 1) * 4096 + aoff);
    COMPUTE(aA, ch);
    if (ch < 14) LOADA(aA, w2c + (ch + 2) * 4096 + aoff);
    COMPUTE(aB, ch + 1);
  }

  // Phase B epilogue: out-col reduction fully in-lane (w3 wave-uniform per reg)
  float part0 = 0.f, part1 = 0.f;
#pragma unroll
  for (int mi = 0; mi < 2; ++mi)
#pragma unroll
    for (int g = 0; g < 4; ++g) {
      f32x4 wlo = *(const f32x4*)(w3 + bidx + mi * 32 + g * 8);
      f32x4 whi = *(const f32x4*)(w3 + bidx + mi * 32 + g * 8 + 4);
#pragma unroll
      for (int r = 0; r < 4; ++r) {
        float wv = hiH ? whi[r] : wlo[r];
        part0 += fmaxf(acc[mi][0][g * 4 + r], 0.f) * wv;
        part1 += fmaxf(acc[mi][1][g * 4 + r], 0.f) * wv;
      }
    }
  red[(wq * 2 + hi) * 128 + n_base + l31]      = part0;
  red[(wq * 2 + hi) * 128 + n_base + 32 + l31] = part1;
  __syncthreads();
  if (t < 128) {
    float v = b3[c];
#pragma unroll
    for (int k = 0; k < 8; ++k) v += red[k * 128 + t];
    out[(b0 + t) * 256 + c] = v;
  }
#undef LOADA
#undef COMPUTE
#undef INIT_ACC
}

// ---------- launcher ----------
extern "C" void kernel_launch(void* const* d_in, const int* in_sizes, int n_in,
                              void* d_out, int out_size, void* d_ws, size_t ws_size,
                              hipStream_t stream) {
  const float* x  = (const float*)d_in[0];
  const float* W1 = (const float*)d_in[1];
  const float* b1 = (const float*)d_in[2];
  const float* W2 = (const float*)d_in[3];
  const float* b2 = (const float*)d_in[4];
  const float* W3 = (const float*)d_in[5];
  const float* b3 = (const float*)d_in[6];
  float* out = (float*)d_out;

  char* ws = (char*)d_ws;
  u16* xb  = (u16*)ws;                                   // 1 MB
  u16* w1t = (u16*)(ws + (1u << 20));                    // 32 MB
  u16* w2t = (u16*)(ws + (1u << 20) + (32u << 20));      // 32 MB

  convert_x_k   <<<512,  256, 0, stream>>>(x,  xb);
  transpose_w2_k<<<8192, 256, 0, stream>>>(W1, W2, w1t, w2t);
  rf_main_k     <<<4096, 512, 0, stream>>>(xb, w1t, w2t, b1, b2, W3, b3, out);
}